// Round 13
// baseline (900.072 us; speedup 1.0000x reference)
//
#include <hip/hip_runtime.h>

#define N_USERS 100000
#define N_ITEMS 50000
#define N_NODES 150000
#define EMBED_DIM 64
#define N_EDGES 4800000
#define N_LAYERS 3

// two-level row radix: coarse buckets of 512 rows
#define CB_SHIFT 9
#define CB_ROWS (1 << CB_SHIFT)                          // 512
#define NC ((N_NODES + CB_ROWS - 1) >> CB_SHIFT)         // 293

// col slices for L2-windowed gathering
#define SLICE_SHIFT 14                                   // 16384 cols = 2MB bf16 x
#define NSLICE 10                                        // covers 163840 >= 150000

// rows per wave in the sliced SpMV
#define RPW 19
#define NWAVES ((N_NODES + RPW - 1) / RPW)               // 7895
#define SPMV_BLOCKS ((NWAVES * 64 + 255) / 256)          // 1974

#define EPB_A 16384                                      // edges per block (hist)
#define NPB_A ((N_EDGES + EPB_A - 1) / EPB_A)            // 293
#define EPB_C 8192                                       // edges per block (partition)
#define NPB_C ((N_EDGES + EPB_C - 1) / EPB_C)            // 586
#define INIT_BLOCKS ((N_NODES * EMBED_DIM / 4 + 255) / 256)   // 9375

// ---------- bf16 helpers (RNE) ----------
__device__ __forceinline__ unsigned short f2bf(float f) {
    unsigned u = __float_as_uint(f);
    u += 0x7fffu + ((u >> 16) & 1u);
    return (unsigned short)(u >> 16);
}
__device__ __forceinline__ float bf2f(unsigned short h) {
    return __uint_as_float((unsigned)h << 16);
}

// ---------------- fused: coarse histogram + init cur0=bf16(emb) ----------------
__global__ __launch_bounds__(256)
void k_hist_init(const int* __restrict__ row, int* __restrict__ c_cnt,
                 const float* __restrict__ user_emb,
                 const float* __restrict__ item_emb,
                 unsigned short* __restrict__ curb) {
    __shared__ int h[NC];
    int blk = blockIdx.x;
    if (blk < NPB_A) {
        for (int i = threadIdx.x; i < NC; i += 256) h[i] = 0;
        __syncthreads();
        int e0 = blk * EPB_A;
        int e1 = e0 + EPB_A; if (e1 > N_EDGES) e1 = N_EDGES;
        for (int e = e0 + threadIdx.x; e < e1; e += 256)
            atomicAdd(&h[row[e] >> CB_SHIFT], 1);
        __syncthreads();
        for (int i = threadIdx.x; i < NC; i += 256)
            if (h[i]) atomicAdd(&c_cnt[i], h[i]);
    } else {
        int i = (blk - NPB_A) * 256 + threadIdx.x;
        const int total = N_NODES * EMBED_DIM / 4;
        if (i >= total) return;
        const int user_elems = N_USERS * EMBED_DIM / 4;
        float4 v;
        if (i < user_elems) v = ((const float4*)user_emb)[i];
        else                v = ((const float4*)item_emb)[i - user_elems];
        ushort4 o;
        o.x = f2bf(v.x); o.y = f2bf(v.y); o.z = f2bf(v.z); o.w = f2bf(v.w);
        ((ushort4*)curb)[i] = o;
    }
}

// ---------------- scan of 293 coarse counts ----------------
#define SCAN_T 256
#define SCAN_C ((NC + SCAN_T - 1) / SCAN_T)   // 2
__global__ void k_scan(const int* __restrict__ c_cnt,
                       int* __restrict__ cbase,
                       int* __restrict__ ccur) {
    __shared__ int part[SCAN_T];
    int t = threadIdx.x;
    int c0 = t * SCAN_C;
    int local[SCAN_C];
    int run = 0;
    for (int k = 0; k < SCAN_C; ++k) {
        int i = c0 + k;
        int v = (i < NC) ? c_cnt[i] : 0;
        local[k] = run;
        run += v;
    }
    part[t] = run;
    __syncthreads();
    if (t == 0) {
        int r2 = 0;
        for (int i = 0; i < SCAN_T; ++i) { int v = part[i]; part[i] = r2; r2 += v; }
    }
    __syncthreads();
    int base = part[t];
    for (int k = 0; k < SCAN_C; ++k) {
        int i = c0 + k;
        if (i < NC) {
            int v = base + local[k];
            cbase[i] = v;
            ccur[i]  = v;
        }
    }
    if (t == 0) cbase[NC] = N_EDGES;
}

// ---------------- coarse partition into 293 segments ----------------
// packed edge: (col << 9) | row_local(9b), val bits (int2)
__global__ __launch_bounds__(256)
void k_part_c(const int* __restrict__ row,
              const int* __restrict__ col,
              const int* __restrict__ valI,
              int* __restrict__ ccur,
              int2* __restrict__ edges) {
    __shared__ int h[NC];
    __shared__ int off[NC];
    int e0 = blockIdx.x * EPB_C;
    int e1 = e0 + EPB_C; if (e1 > N_EDGES) e1 = N_EDGES;
    for (int i = threadIdx.x; i < NC; i += 256) h[i] = 0;
    __syncthreads();
    for (int e = e0 + threadIdx.x; e < e1; e += 256)
        atomicAdd(&h[row[e] >> CB_SHIFT], 1);
    __syncthreads();
    for (int i = threadIdx.x; i < NC; i += 256)
        if (h[i]) off[i] = atomicAdd(&ccur[i], h[i]);
    __syncthreads();
    for (int e = e0 + threadIdx.x; e < e1; e += 256) {
        int r = row[e];
        int cb = r >> CB_SHIFT;
        int p = atomicAdd(&off[cb], 1);
        edges[p] = make_int2((col[e] << CB_SHIFT) | (r & (CB_ROWS - 1)), valI[e]);
    }
}

// ---------------- fine counting sort by (row_local, col_slice) ------------
// one 512-thread block per coarse bucket; emits csr as pure (col,val) and
// rsp[row*NSLICE+s] = start of the (row, slice) segment.
__global__ __launch_bounds__(512)
void k_sort_sl(const int* __restrict__ cbase,
               const int2* __restrict__ edges,
               int2* __restrict__ csr,
               int* __restrict__ rsp) {
    __shared__ int h[CB_ROWS * NSLICE];     // 5120
    __shared__ int off[CB_ROWS * NSLICE];   // 5120
    __shared__ int part[512];
    int b = blockIdx.x, t = threadIdx.x;
    int seg0 = cbase[b], seg1 = cbase[b + 1];
    for (int i = t; i < CB_ROWS * NSLICE; i += 512) h[i] = 0;
    __syncthreads();
    for (int e = seg0 + t; e < seg1; e += 512) {
        int2 ee = edges[e];
        int col = ee.x >> CB_SHIFT;
        int bin = (ee.x & (CB_ROWS - 1)) * NSLICE + (col >> SLICE_SHIFT);
        atomicAdd(&h[bin], 1);
    }
    __syncthreads();
    // thread t owns row_local t's NSLICE bins: serial local scan
    int loc[NSLICE];
    int run = 0;
    #pragma unroll
    for (int s = 0; s < NSLICE; ++s) { loc[s] = run; run += h[t * NSLICE + s]; }
    part[t] = run;
    __syncthreads();
    // Hillis-Steele inclusive scan over 512 per-row totals
    for (int o = 1; o < 512; o <<= 1) {
        int v = (t >= o) ? part[t - o] : 0;
        __syncthreads();
        part[t] += v;
        __syncthreads();
    }
    int base = t ? part[t - 1] : 0;
    int row0 = b << CB_SHIFT;
    int nrows = N_NODES - row0; if (nrows > CB_ROWS) nrows = CB_ROWS;
    #pragma unroll
    for (int s = 0; s < NSLICE; ++s) {
        int excl = base + loc[s];
        off[t * NSLICE + s] = excl;
        if (t < nrows) rsp[(size_t)(row0 + t) * NSLICE + s] = seg0 + excl;
    }
    __syncthreads();
    for (int e = seg0 + t; e < seg1; e += 512) {
        int2 ee = edges[e];
        int col = ee.x >> CB_SHIFT;
        int bin = (ee.x & (CB_ROWS - 1)) * NSLICE + (col >> SLICE_SHIFT);
        int p = atomicAdd(&off[bin], 1);
        csr[seg0 + p] = make_int2(col, ee.y);   // (col, val bits)
    }
    if (b == NC - 1 && t == 0) rsp[(size_t)N_NODES * NSLICE] = N_EDGES;
}

// ---------------- sliced persistent-wave SpMV ----------------
// each wave owns RPW consecutive rows with acc in registers; all waves sweep
// col-slices 0..9 in order -> instantaneous gather working set ~2MB (L2-hot).
__global__ __launch_bounds__(256)
void lgcn_spmv_sl(const int* __restrict__ rsp,
                  const int2* __restrict__ cv,          // (col, val bits)
                  const unsigned short* __restrict__ x, // bf16 [N][64]
                  unsigned short* __restrict__ nxt,     // if !last
                  const unsigned short* __restrict__ e1,// if last
                  const float* __restrict__ user_emb,
                  const float* __restrict__ item_emb,
                  float* __restrict__ out,              // if last
                  int last) {
    int t = blockIdx.x * blockDim.x + threadIdx.x;
    int wave = t >> 6;
    int lane = t & 63;
    int r0 = __builtin_amdgcn_readfirstlane(wave) * RPW;
    if (r0 >= N_NODES) return;
    float acc[RPW];
    #pragma unroll
    for (int k = 0; k < RPW; ++k) acc[k] = 0.f;

    for (int s = 0; s < NSLICE; ++s) {
        #pragma unroll
        for (int k = 0; k < RPW; ++k) {
            int r = r0 + k;
            if (r < N_NODES) {
                int j    = rsp[r * NSLICE + s];
                int jend = rsp[r * NSLICE + s + 1];
                for (; j + 2 <= jend; j += 2) {
                    int2 e0 = cv[j], e1_ = cv[j + 1];
                    float xa = bf2f(x[((size_t)e0.x  << 6) + lane]);
                    float xb = bf2f(x[((size_t)e1_.x << 6) + lane]);
                    acc[k] += __int_as_float(e0.y)  * xa;
                    acc[k] += __int_as_float(e1_.y) * xb;
                }
                if (j < jend) {
                    int2 e = cv[j];
                    acc[k] += __int_as_float(e.y) * bf2f(x[((size_t)e.x << 6) + lane]);
                }
            }
        }
    }

    #pragma unroll
    for (int k = 0; k < RPW; ++k) {
        int r = r0 + k;
        if (r < N_NODES) {
            size_t o = ((size_t)r << 6) + lane;
            if (!last) {
                nxt[o] = f2bf(acc[k]);
            } else {
                float e0 = (r < N_USERS) ? user_emb[o]
                                         : item_emb[o - ((size_t)N_USERS << 6)];
                float v = ((e0 + bf2f(e1[o])) + bf2f(x[o])) + acc[k];
                out[o] = v * 0.25f;
            }
        }
    }
}

// ---------------- fallback (atomic scatter, f32) ----------------
__global__ void lgcn_init(const float* __restrict__ user_emb,
                          const float* __restrict__ item_emb,
                          float* __restrict__ cur,
                          float* __restrict__ acc) {
    int i = blockIdx.x * blockDim.x + threadIdx.x;
    const int total = N_NODES * EMBED_DIM / 4;
    if (i >= total) return;
    const int user_elems = N_USERS * EMBED_DIM / 4;
    float4 v;
    if (i < user_elems) v = ((const float4*)user_emb)[i];
    else                v = ((const float4*)item_emb)[i - user_elems];
    ((float4*)cur)[i] = v;
    ((float4*)acc)[i] = v;
}

__global__ void lgcn_spmm_atomic(const int* __restrict__ row,
                                 const int* __restrict__ col,
                                 const float* __restrict__ val,
                                 const float* __restrict__ x,
                                 float* __restrict__ y) {
    long long t = (long long)blockIdx.x * blockDim.x + threadIdx.x;
    int e = (int)(t >> 6);
    int d = (int)(t & 63);
    if (e >= N_EDGES) return;
    atomicAdd(&y[(long long)row[e] * EMBED_DIM + d],
              val[e] * x[(long long)col[e] * EMBED_DIM + d]);
}

__global__ void lgcn_accum(const float* __restrict__ cur,
                           float* __restrict__ acc, float s) {
    int i = blockIdx.x * blockDim.x + threadIdx.x;
    const int total = N_NODES * EMBED_DIM / 4;
    if (i >= total) return;
    float4 a = ((const float4*)acc)[i];
    float4 c = ((const float4*)cur)[i];
    a.x = (a.x + c.x) * s; a.y = (a.y + c.y) * s;
    a.z = (a.z + c.z) * s; a.w = (a.w + c.w) * s;
    ((float4*)acc)[i] = a;
}

extern "C" void kernel_launch(void* const* d_in, const int* in_sizes, int n_in,
                              void* d_out, int out_size, void* d_ws, size_t ws_size,
                              hipStream_t stream) {
    const int*   adj_row  = (const int*)d_in[0];
    const int*   adj_col  = (const int*)d_in[1];
    const float* adj_val  = (const float*)d_in[2];
    const int*   adj_valI = (const int*)d_in[2];
    const float* user_emb = (const float*)d_in[3];
    const float* item_emb = (const float*)d_in[4];
    float* out = (float*)d_out;

    const size_t buf_elems = (size_t)N_NODES * EMBED_DIM;

    // ---- workspace layout ----
    char* wp = (char*)d_ws;
    int* c_cnt  = (int*)wp;  wp += (size_t)NC * sizeof(int);
    int* cbase  = (int*)wp;  wp += (size_t)(NC + 1) * sizeof(int);
    int* ccur   = (int*)wp;  wp += (size_t)NC * sizeof(int);
    wp = (char*)(((size_t)wp + 63) & ~(size_t)63);
    int* rsp    = (int*)wp;  wp += ((size_t)N_NODES * NSLICE + 1) * sizeof(int);
    wp = (char*)(((size_t)wp + 63) & ~(size_t)63);
    int2* edges  = (int2*)wp; wp += (size_t)N_EDGES * sizeof(int2);
    wp = (char*)(((size_t)wp + 63) & ~(size_t)63);
    int2* csr_cv = (int2*)wp; wp += (size_t)N_EDGES * sizeof(int2);
    wp = (char*)(((size_t)wp + 63) & ~(size_t)63);
    unsigned short* curb = (unsigned short*)wp; wp += buf_elems * sizeof(unsigned short);
    unsigned short* nxtb = (unsigned short*)wp; wp += buf_elems * sizeof(unsigned short);
    size_t needed = (size_t)(wp - (char*)d_ws);
    // e2 buffer aliases the (dead-after-sort) edges region
    unsigned short* e2b = (unsigned short*)edges;

    if (needed <= ws_size) {
        // ---- build: fused hist+init, scan, coarse partition, sliced sort ----
        hipMemsetAsync(c_cnt, 0, NC * sizeof(int), stream);
        k_hist_init<<<NPB_A + INIT_BLOCKS, 256, 0, stream>>>(adj_row, c_cnt,
                                                             user_emb, item_emb, curb);
        k_scan<<<1, SCAN_T, 0, stream>>>(c_cnt, cbase, ccur);
        k_part_c<<<NPB_C, 256, 0, stream>>>(adj_row, adj_col, adj_valI, ccur, edges);
        k_sort_sl<<<NC, 512, 0, stream>>>(cbase, edges, csr_cv, rsp);

        // ---- 3 sliced SpMV layers; acc deferred into the last ----
        // L1: curb -> nxtb (e1)
        lgcn_spmv_sl<<<SPMV_BLOCKS, 256, 0, stream>>>(rsp, csr_cv, curb, nxtb,
                                                      nullptr, nullptr, nullptr, nullptr, 0);
        // L2: nxtb -> e2b (aliases edges)
        lgcn_spmv_sl<<<SPMV_BLOCKS, 256, 0, stream>>>(rsp, csr_cv, nxtb, e2b,
                                                      nullptr, nullptr, nullptr, nullptr, 0);
        // L3: gather from e2b, combine with e0 (f32 inputs) + e1 + e2 -> out
        lgcn_spmv_sl<<<SPMV_BLOCKS, 256, 0, stream>>>(rsp, csr_cv, e2b, nullptr,
                                                      nxtb, user_emb, item_emb, out, 1);
    } else {
        // ---- fallback: atomic path (f32) ----
        float* curF = (float*)d_ws;
        float* nxtF = curF + buf_elems;
        const int total = N_NODES * EMBED_DIM / 4;
        lgcn_init<<<(total + 255) / 256, 256, 0, stream>>>(user_emb, item_emb, curF, out);
        float* a = curF; float* b = nxtF;
        for (int layer = 0; layer < N_LAYERS; ++layer) {
            hipMemsetAsync(b, 0, buf_elems * sizeof(float), stream);
            long long tthr = (long long)N_EDGES * 64;
            lgcn_spmm_atomic<<<(unsigned)((tthr + 255) / 256), 256, 0, stream>>>(
                adj_row, adj_col, adj_val, a, b);
            float s = (layer == N_LAYERS - 1) ? (1.0f / (N_LAYERS + 1)) : 1.0f;
            lgcn_accum<<<(total + 255) / 256, 256, 0, stream>>>(b, out, s);
            float* t = a; a = b; b = t;
        }
    }
}